// Round 4
// baseline (860.663 us; speedup 1.0000x reference)
//
#include <hip/hip_runtime.h>

// GraphDiTPolicy fused kernel for MI355X (gfx950).
// B=32768, N=2, T=4, D=256, H=8, E=2, HD=32, S=8.
// Inputs fp32 (runtime-detected), OUTPUT FP32 (proven round 3: bf16 writes
// read back as scrambled fp32 -> err 0.184 identical across two different
// implementations). MFMA everywhere: QKV GEMM, scores, PV, out-proj.

typedef short bf16x8 __attribute__((ext_vector_type(8)));
typedef float f32x4 __attribute__((ext_vector_type(4)));
typedef unsigned short u16;

#define SCALE_F 0.17677669529663687f   // 1/sqrt(32)
#define WT_BYTES (1024 * 256 * 2)      // (768+256) rows x 256 cols x 2B

__device__ __forceinline__ float bf2f(u16 h) {
  unsigned u = ((unsigned)h) << 16; float f; __builtin_memcpy(&f, &u, 4); return f;
}
__device__ __forceinline__ u16 f2bf(float f) {
  unsigned u; __builtin_memcpy(&u, &f, 4);
  u += 0x7FFFu + ((u >> 16) & 1u);
  return (u16)(u >> 16);
}

template<bool F32>
__device__ __forceinline__ float LD(const void* p, int i) {
  if constexpr (F32) return ((const float*)p)[i];
  else return bf2f(((const u16*)p)[i]);
}

template<bool F32>
__device__ __forceinline__ bf16x8 load8bf(const void* p, int idx) {
  if constexpr (F32) {
    const float* f = (const float*)p + idx;
    float4 a = *(const float4*)f;
    float4 b = *(const float4*)(f + 4);
    bf16x8 r;
    r[0] = (short)f2bf(a.x); r[1] = (short)f2bf(a.y);
    r[2] = (short)f2bf(a.z); r[3] = (short)f2bf(a.w);
    r[4] = (short)f2bf(b.x); r[5] = (short)f2bf(b.y);
    r[6] = (short)f2bf(b.z); r[7] = (short)f2bf(b.w);
    return r;
  } else {
    return *(const bf16x8*)((const u16*)p + idx);
  }
}

// fp32-vs-bf16 detection on x's raw u16s (even halves wild for fp32).
__global__ void detect_kernel(const u16* __restrict__ x16, int* __restrict__ flag) {
  __shared__ int tot;
  if (threadIdx.x == 0) tot = 0;
  __syncthreads();
  int cnt = 0;
  for (int i = threadIdx.x; i < 4096; i += 256) {
    int e = (x16[2 * i] >> 7) & 0xFF;
    cnt += (e >= 0x90 || e <= 0x50) ? 1 : 0;
  }
  atomicAdd(&tot, cnt);
  __syncthreads();
  if (threadIdx.x == 0) *flag = (tot >= 64) ? 1 : 0;
}

// WT[n][k] = W[k][n] (bf16): rows 0-255 Wq cols, 256-511 Wk, 512-767 Wv,
// 768-1023 Wo cols. One 16B load = one MFMA B-fragment slice.
__global__ void prep_kernel(const void* __restrict__ Wq, const void* __restrict__ Wk,
                            const void* __restrict__ Wv, const void* __restrict__ Wo,
                            const int* __restrict__ flag, u16* __restrict__ WT) {
  const bool f32 = (*flag != 0);
  int n = blockIdx.x;
  int k = threadIdx.x;
  if (n < 768) {
    int sel = n >> 8, col = n & 255;
    const void* src = sel == 0 ? Wq : (sel == 1 ? Wk : Wv);
    float v = f32 ? ((const float*)src)[k * 256 + col] : bf2f(((const u16*)src)[k * 256 + col]);
    WT[n * 256 + k] = f2bf(v);
  } else {
    int col = n - 768;
    float v = f32 ? ((const float*)Wo)[k * 256 + col] : bf2f(((const u16*)Wo)[k * 256 + col]);
    WT[768 * 256 + col * 256 + k] = f2bf(v);
  }
}

struct __align__(16) SharedMem {
  u16 qk[4][32][72];    // [wave][xrow][Q 0-31 | K 32-63 | pad]
  u16 vt[4][32][56];    // [wave][d][xrow], cols 32-55 stay zero
  u16 pb[4][16][40];    // [wave][s'][t-col], cols 16-31 stay zero
  u16 pooled[32][264];  // [(batch*2+node) block-local][dim]
};

template<bool F32>
__device__ __forceinline__ void fused_impl(
    SharedMem& sm,
    const void* __restrict__ x, const void* __restrict__ edge,
    const void* __restrict__ bq, const void* __restrict__ bk, const void* __restrict__ bv,
    const void* __restrict__ bo,
    const void* __restrict__ Wbias, const void* __restrict__ bbias,
    const void* __restrict__ Wgate, const void* __restrict__ bgate,
    const void* __restrict__ Wscale, const void* __restrict__ bscale,
    const void* __restrict__ Wshift, const void* __restrict__ bshift,
    const void* __restrict__ Whs, const void* __restrict__ bhs,
    const u16* __restrict__ WT, float* __restrict__ out) {
  const int tid = threadIdx.x;
  const int w  = tid >> 6;     // wave 0..3, owns batches w*4..w*4+3
  const int l  = tid & 63;
  const int ln = l & 15;
  const int q4 = l >> 4;       // quad group 0..3

  // zero vt cols 32-55 region + pb cols 16-31 region (K-padding must be 0)
  {
    u16* vz = &sm.vt[w][0][0];
#pragma unroll
    for (int i = 0; i < 28; ++i) vz[l + 64 * i] = 0;   // 32*56 = 1792
    u16* pz = &sm.pb[w][0][0];
#pragma unroll
    for (int i = 0; i < 10; ++i) pz[l + 64 * i] = 0;   // 16*40 = 640
  }

  // X rows as MFMA A-fragments: lane holds X[mt*16+ln][ks*32 + q4*8 + j]
  const int xbase = (blockIdx.x * 128 + w * 32) * 256;
  bf16x8 xa[2][8];
#pragma unroll
  for (int mt = 0; mt < 2; ++mt)
#pragma unroll
    for (int ks = 0; ks < 8; ++ks)
      xa[mt][ks] = load8bf<F32>(x, xbase + (mt * 16 + ln) * 256 + ks * 32 + q4 * 8);

#pragma unroll 1
  for (int h = 0; h < 8; ++h) {
    // ---------- QKV GEMM head h: [32 rows] x [96 cols] x K=256 ----------
    f32x4 acc[2][6];
#pragma unroll
    for (int mt = 0; mt < 2; ++mt)
#pragma unroll
      for (int nt = 0; nt < 6; ++nt) acc[mt][nt] = (f32x4){0.f, 0.f, 0.f, 0.f};

    const u16* wp[6];
#pragma unroll
    for (int nt = 0; nt < 6; ++nt) {
      int nrow = (nt >> 1) * 256 + h * 32 + (nt & 1) * 16 + ln;
      wp[nt] = WT + nrow * 256 + q4 * 8;
    }
#pragma unroll
    for (int ks = 0; ks < 8; ++ks) {
      bf16x8 bfr[6];
#pragma unroll
      for (int nt = 0; nt < 6; ++nt) bfr[nt] = *(const bf16x8*)(wp[nt] + ks * 32);
#pragma unroll
      for (int nt = 0; nt < 6; ++nt) {
        acc[0][nt] = __builtin_amdgcn_mfma_f32_16x16x32_bf16(xa[0][ks], bfr[nt], acc[0][nt], 0, 0, 0);
        acc[1][nt] = __builtin_amdgcn_mfma_f32_16x16x32_bf16(xa[1][ks], bfr[nt], acc[1][nt], 0, 0, 0);
      }
    }

    // ---------- epilogue: Q,K (+bias) row-major to LDS ----------
#pragma unroll
    for (int nt = 0; nt < 4; ++nt) {
      int cb = (nt & 1) * 16 + ln;                       // 0..31 within head
      float bias = LD<F32>((nt >> 1) ? bk : bq, h * 32 + cb);
      int col = (nt >> 1) * 32 + cb;                     // Q: 0-31, K: 32-63
#pragma unroll
      for (int mt = 0; mt < 2; ++mt)
#pragma unroll
        for (int r = 0; r < 4; ++r)
          sm.qk[w][mt * 16 + q4 * 4 + r][col] = f2bf(acc[mt][nt][r] + bias);
    }
    // ---------- epilogue: V with edge modulation, stored transposed ----------
#pragma unroll
    for (int nt = 4; nt < 6; ++nt) {
      int dg = h * 32 + (nt - 4) * 16 + ln;              // global dim
      float bvv = LD<F32>(bv, dg);
      float wg0 = LD<F32>(Wgate, dg),  wg1 = LD<F32>(Wgate, 256 + dg),  bg  = LD<F32>(bgate, dg);
      float ws0 = LD<F32>(Wscale, dg), ws1 = LD<F32>(Wscale, 256 + dg), bs  = LD<F32>(bscale, dg);
      float wf0 = LD<F32>(Wshift, dg), wf1 = LD<F32>(Wshift, 256 + dg), bsh = LD<F32>(bshift, dg);
#pragma unroll
      for (int mt = 0; mt < 2; ++mt) {
        int gb = blockIdx.x * 16 + w * 4 + mt * 2 + (q4 >> 1);  // this lane's batch
        float e0 = LD<F32>(edge, gb * 2), e1 = LD<F32>(edge, gb * 2 + 1);
        float ga = 1.f / (1.f + __expf(-(e0 * wg0 + e1 * wg1 + bg)));
        float sc = tanhf(e0 * ws0 + e1 * ws1 + bs);
        float sh = e0 * wf0 + e1 * wf1 + bsh;
        u16 vv[4];
#pragma unroll
        for (int r = 0; r < 4; ++r) {
          float v = acc[mt][nt][r] + bvv;
          v = (v * (1.f + sc) + sh) * ga;
          vv[r] = f2bf(v);
        }
        ushort4 pk; pk.x = vv[0]; pk.y = vv[1]; pk.z = vv[2]; pk.w = vv[3];
        *(ushort4*)&sm.vt[w][(nt - 4) * 16 + ln][mt * 16 + q4 * 4] = pk;
      }
    }
    __asm__ volatile("" ::: "memory");  // wave-private LDS; DS ops in-order

    // ---------- attention: 2 batches packed per 16x16 tile ----------
    float wb0 = LD<F32>(Wbias, h), wb1 = LD<F32>(Wbias, 8 + h), bb  = LD<F32>(bbias, h);
    float wh0 = LD<F32>(Whs, h),   wh1 = LD<F32>(Whs, 8 + h),   bh_ = LD<F32>(bhs, h);
#pragma unroll
    for (int pair = 0; pair < 2; ++pair) {
      bf16x8 qa = *(const bf16x8*)&sm.qk[w][pair * 16 + ln][q4 * 8];       // Q rows
      bf16x8 kb = *(const bf16x8*)&sm.qk[w][pair * 16 + ln][32 + q4 * 8];  // K rows
      f32x4 z4 = {0.f, 0.f, 0.f, 0.f};
      f32x4 s = __builtin_amdgcn_mfma_f32_16x16x32_bf16(qa, kb, z4, 0, 0, 0);

      int gb0 = blockIdx.x * 16 + w * 4 + pair * 2;
      float e00 = LD<F32>(edge, gb0 * 2),     e01 = LD<F32>(edge, gb0 * 2 + 1);
      float e10 = LD<F32>(edge, gb0 * 2 + 2), e11 = LD<F32>(edge, gb0 * 2 + 3);
      float eb0 = e00 * wb0 + e01 * wb1 + bb;
      float eb1 = e10 * wb0 + e11 * wb1 + bb;
      float hs0 = tanhf(e00 * wh0 + e01 * wh1 + bh_);
      float hs1 = tanhf(e10 * wh0 + e11 * wh1 + bh_);
      int bj = ln >> 3;                       // column batch within pair
      float mult = SCALE_F * (1.f + (bj ? hs1 : hs0));
      float ebias = bj ? eb1 : eb0;
      int tl = ln & 7;
      bool valid = ((q4 >> 1) == bj);         // row batch == col batch
      float p[4];
#pragma unroll
      for (int r = 0; r < 4; ++r) {
        int sl = (q4 & 1) * 4 + r;            // s within batch
        p[r] = s[r] * mult + ((tl == (sl ^ 4)) ? ebias : 0.f);  // sparse bias
      }
      // softmax over t (8-lane groups)
#pragma unroll
      for (int r = 0; r < 4; ++r) {
        float m = p[r];
        m = fmaxf(m, __shfl_xor(m, 1));
        m = fmaxf(m, __shfl_xor(m, 2));
        m = fmaxf(m, __shfl_xor(m, 4));
        float e = __expf(p[r] - m);
        float su = e;
        su += __shfl_xor(su, 1);
        su += __shfl_xor(su, 2);
        su += __shfl_xor(su, 4);
        p[r] = e / su;
      }
#pragma unroll
      for (int r = 0; r < 4; ++r)
        sm.pb[w][q4 * 4 + r][ln] = valid ? f2bf(p[r]) : (u16)0;
      __asm__ volatile("" ::: "memory");

      // P.V via MFMA; lane's 4 C rows = one (batch,node)'s T rows -> free mean
      bf16x8 pa = *(const bf16x8*)&sm.pb[w][ln][q4 * 8];
#pragma unroll
      for (int nt = 0; nt < 2; ++nt) {
        bf16x8 vb = *(const bf16x8*)&sm.vt[w][nt * 16 + ln][pair * 16 + q4 * 8];
        f32x4 z = {0.f, 0.f, 0.f, 0.f};
        f32x4 o = __builtin_amdgcn_mfma_f32_16x16x32_bf16(pa, vb, z, 0, 0, 0);
        float pm = (o[0] + o[1] + o[2] + o[3]) * 0.25f;   // mean over T=4
        int prow = w * 8 + (pair * 2 + (q4 >> 1)) * 2 + (q4 & 1);
        sm.pooled[prow][h * 32 + nt * 16 + ln] = f2bf(pm);
      }
    }
  }

  // ---------- final projection: pooled[32][256] @ Wo + bo (fp32 out) ----------
  __syncthreads();
  const u16* WoT = WT + 768 * 256;
  f32x4 fo[2][4];
#pragma unroll
  for (int mt = 0; mt < 2; ++mt)
#pragma unroll
    for (int nt = 0; nt < 4; ++nt) fo[mt][nt] = (f32x4){0.f, 0.f, 0.f, 0.f};
#pragma unroll
  for (int ks = 0; ks < 8; ++ks) {
    bf16x8 af0 = *(const bf16x8*)&sm.pooled[ln][ks * 32 + q4 * 8];
    bf16x8 af1 = *(const bf16x8*)&sm.pooled[16 + ln][ks * 32 + q4 * 8];
#pragma unroll
    for (int ntw = 0; ntw < 4; ++ntw) {
      int nrow = w * 64 + ntw * 16 + ln;
      bf16x8 bfr = *(const bf16x8*)(WoT + nrow * 256 + ks * 32 + q4 * 8);
      fo[0][ntw] = __builtin_amdgcn_mfma_f32_16x16x32_bf16(af0, bfr, fo[0][ntw], 0, 0, 0);
      fo[1][ntw] = __builtin_amdgcn_mfma_f32_16x16x32_bf16(af1, bfr, fo[1][ntw], 0, 0, 0);
    }
  }
#pragma unroll
  for (int ntw = 0; ntw < 4; ++ntw) {
    int col = w * 64 + ntw * 16 + ln;
    float bias = LD<F32>(bo, col);
#pragma unroll
    for (int mt = 0; mt < 2; ++mt)
#pragma unroll
      for (int r = 0; r < 4; ++r) {
        int row = mt * 16 + q4 * 4 + r;       // block-local batch*2+node
        out[(blockIdx.x * 32 + row) * 256 + col] = fo[mt][ntw][r] + bias;  // FP32
      }
  }
}

__global__ __launch_bounds__(256, 2) void fused_kernel(
    const void* __restrict__ x, const void* __restrict__ edge,
    const void* __restrict__ bq, const void* __restrict__ bk, const void* __restrict__ bv,
    const void* __restrict__ bo,
    const void* __restrict__ Wbias, const void* __restrict__ bbias,
    const void* __restrict__ Wgate, const void* __restrict__ bgate,
    const void* __restrict__ Wscale, const void* __restrict__ bscale,
    const void* __restrict__ Wshift, const void* __restrict__ bshift,
    const void* __restrict__ Whs, const void* __restrict__ bhs,
    const int* __restrict__ flag, const u16* __restrict__ WT, float* __restrict__ out) {
  __shared__ SharedMem sm;
  if (*flag)
    fused_impl<true>(sm, x, edge, bq, bk, bv, bo, Wbias, bbias, Wgate, bgate,
                     Wscale, bscale, Wshift, bshift, Whs, bhs, WT, out);
  else
    fused_impl<false>(sm, x, edge, bq, bk, bv, bo, Wbias, bbias, Wgate, bgate,
                      Wscale, bscale, Wshift, bshift, Whs, bhs, WT, out);
}

extern "C" void kernel_launch(void* const* d_in, const int* in_sizes, int n_in,
                              void* d_out, int out_size, void* d_ws, size_t ws_size,
                              hipStream_t stream) {
  (void)in_sizes; (void)n_in; (void)out_size; (void)ws_size;
  const void* x      = d_in[0];
  const void* edge   = d_in[1];
  const void* Wq     = d_in[2];  const void* bq  = d_in[3];
  const void* Wk     = d_in[4];  const void* bk  = d_in[5];
  const void* Wv     = d_in[6];  const void* bv  = d_in[7];
  const void* Wo     = d_in[8];  const void* bo  = d_in[9];
  const void* Wbias  = d_in[10]; const void* bbias  = d_in[11];
  const void* Wgate  = d_in[12]; const void* bgate  = d_in[13];
  const void* Wscale = d_in[14]; const void* bscale = d_in[15];
  const void* Wshift = d_in[16]; const void* bshift = d_in[17];
  const void* Whs    = d_in[18]; const void* bhs    = d_in[19];
  u16* WT   = (u16*)d_ws;
  int* flag = (int*)((char*)d_ws + WT_BYTES);
  float* out = (float*)d_out;

  detect_kernel<<<1, 256, 0, stream>>>((const u16*)x, flag);
  prep_kernel<<<1024, 256, 0, stream>>>(Wq, Wk, Wv, Wo, flag, WT);
  fused_kernel<<<2048, 256, 0, stream>>>(x, edge, bq, bk, bv, bo, Wbias, bbias,
                                         Wgate, bgate, Wscale, bscale, Wshift, bshift,
                                         Whs, bhs, flag, WT, out);
}